// Round 10
// baseline (314.775 us; speedup 1.0000x reference)
//
#include <hip/hip_runtime.h>
#include <math.h>

// Problem constants (match reference)
#define NQ 16384
#define NK 7933
#define DI 1024
#define HD 512
#define RANK_TARGET 11469   // NQ - int(0.3*NQ): 0-based ascending rank of thre

typedef __bf16 bf16x8 __attribute__((ext_vector_type(8)));
typedef float  f32x4  __attribute__((ext_vector_type(4)));

#define GLOAD_LDS16(g, l)                                                     \
  __builtin_amdgcn_global_load_lds(                                           \
      (const __attribute__((address_space(1))) void*)(g),                     \
      (__attribute__((address_space(3))) void*)(l), 16, 0, 0)

__device__ __forceinline__ unsigned mapf(float f) {
  unsigned b = __float_as_uint(f);
  return (b & 0x80000000u) ? ~b : (b | 0x80000000u);
}

__device__ __forceinline__ bf16x8 cvt8(float4 a, float4 b) {
  bf16x8 o;
  o[0] = (__bf16)a.x; o[1] = (__bf16)a.y; o[2] = (__bf16)a.z; o[3] = (__bf16)a.w;
  o[4] = (__bf16)b.x; o[5] = (__bf16)b.y; o[6] = (__bf16)b.z; o[7] = (__bf16)b.w;
  return o;
}

// ---------------------------------------------------------------------------
// Kernel 1: fp32 -> bf16 for wq_w, wk_w, key_x. Block 0 zeroes v/z/scf
// (1088 uints: v[512], z[512], scf[64] incl. the two last-block tickets).
// ---------------------------------------------------------------------------
__global__ void conv_wk(const float* __restrict__ wq, const float* __restrict__ wk,
                        const float* __restrict__ key,
                        __bf16* __restrict__ wqbf, __bf16* __restrict__ wkbf,
                        __bf16* __restrict__ kbf, unsigned* __restrict__ zero_region) {
  if (blockIdx.x == 0) {
    for (int j = threadIdx.x; j < 1088; j += 256) zero_region[j] = 0u;
  }
  const int NK8 = NK * DI / 8;   // 1,015,424
  const int W8  = HD * DI / 8;   // 65,536
  const int total = NK8 + 2 * W8;
  int i = blockIdx.x * blockDim.x + threadIdx.x;
  int stride = gridDim.x * blockDim.x;
  for (; i < total; i += stride) {
    const float* s; __bf16* d; int j;
    if (i < NK8)            { s = key; d = kbf;  j = i; }
    else if (i < NK8 + W8)  { s = wq;  d = wqbf; j = i - NK8; }
    else                    { s = wk;  d = wkbf; j = i - NK8 - W8; }
    float4 a = ((const float4*)s)[2 * j];
    float4 b = ((const float4*)s)[2 * j + 1];
    ((bf16x8*)d)[j] = cvt8(a, b);
  }
}

// ---------------------------------------------------------------------------
// Mega kernel, 636 blocks x 512 threads, 80 KB LDS -> 2 blocks/CU.
// Blocks 0..123: k-GEMM 64x512, BK=32, BOTH LDS buffers double-buffered
//   (sA 2x4KB, sB 2x32KB = 72 KB), ONE barrier per K-step, fused v epilogue
//   (no ktanh to HBM; ssrow aliases dead sA).
//   32-col swizzle: slot s of row r holds k-chunk s^((r>>1)&3)  (<=2-way).
// Blocks 124..635: q-GEMM 64x256 reading fp32 query directly (r3/r9-proven
//   reg-staged A), writing qtanh only.
// ---------------------------------------------------------------------------
__global__ __launch_bounds__(512, 4)
void mega_gemms(const __bf16* __restrict__ kbf, const __bf16* __restrict__ wkbf,
                const float* __restrict__ wk_b, const float* __restrict__ wa,
                float* __restrict__ v,
                const float* __restrict__ query, const __bf16* __restrict__ wqbf,
                const float* __restrict__ wq_b, float* __restrict__ qtanh) {
  __shared__ __align__(16) char smem[81920];
  const int bid = blockIdx.x;
  const int tid = threadIdx.x;
  const int lane = tid & 63;
  const int wave = tid >> 6;                    // 0..7
  const int lrow = lane & 15;
  const int chi  = lane >> 4;                   // 0..3
  constexpr int K = DI;

  if (bid < 124) {
    // ------------- k path: 64x512, BK=32, full double-buffer --------------
    __bf16* sA = (__bf16*)smem;                 // 2 x 2048 elems (8 KB)
    __bf16* sB = (__bf16*)(smem + 8192);        // 2 x 16384 elems (64 KB)
    float* ssrow = (float*)smem;                // aliases sA after K-loop
    const int m0 = bid * 64;

    // 32-col staging: lane l -> row l>>2 (16 rows/segment), slot l&3,
    // source chunk (l&3)^((l>>3)&3); LDS dest linear (base + lane*16B).
    const int srow2 = lane >> 2;                         // 0..15
    const int scol2 = ((lane & 3) ^ ((lane >> 3) & 3)) << 3;

    // A: 4 segments of 16 rows; waves 0..3 stage one each.
    const int aseg = wave & 3;
    int garow = m0 + aseg * 16 + srow2; if (garow > NK - 1) garow = NK - 1;
    const __bf16* Ap = kbf + (size_t)garow * K + scol2;
    // B: 32 segments; wave stages segments wave*4 .. wave*4+3.
    const __bf16* Bp[4];
#pragma unroll
    for (int c = 0; c < 4; ++c)
      Bp[c] = wkbf + (size_t)((wave * 4 + c) * 16 + srow2) * K + scol2;

    f32x4 acc[4][4] = {};

    // prologue: stage tile 0 into buffer 0
    if (wave < 4) GLOAD_LDS16(Ap, &sA[aseg * 512]);
#pragma unroll
    for (int c = 0; c < 4; ++c)
      GLOAD_LDS16(Bp[c], &sB[(wave * 4 + c) * 512]);
    __syncthreads();

    int buf = 0;
    for (int t = 0; t < 32; ++t) {
      const int kk = t * 32;
      if (t < 31) {  // fire-and-forget prefetch of tile t+1
        const int ob = buf ^ 1;
        if (wave < 4) GLOAD_LDS16(Ap + kk + 32, &sA[ob * 2048 + aseg * 512]);
#pragma unroll
        for (int c = 0; c < 4; ++c)
          GLOAD_LDS16(Bp[c] + kk + 32, &sB[ob * 16384 + (wave * 4 + c) * 512]);
      }
      const __bf16* sAc = sA + buf * 2048;
      const __bf16* sBc = sB + buf * 16384;
      bf16x8 af[4], bfr[4];
#pragma unroll
      for (int mi = 0; mi < 4; ++mi) {
        const int row = mi * 16 + lrow;
        af[mi] = *(const bf16x8*)(&sAc[row * 32 + ((chi ^ ((row >> 1) & 3)) << 3)]);
      }
#pragma unroll
      for (int ni = 0; ni < 4; ++ni) {
        const int row = wave * 64 + ni * 16 + lrow;
        bfr[ni] = *(const bf16x8*)(&sBc[row * 32 + ((chi ^ ((row >> 1) & 3)) << 3)]);
      }
#pragma unroll
      for (int mi = 0; mi < 4; ++mi)
#pragma unroll
        for (int ni = 0; ni < 4; ++ni)
          acc[mi][ni] = __builtin_amdgcn_mfma_f32_16x16x32_bf16(af[mi], bfr[ni], acc[mi][ni], 0, 0, 0);
      if (t < 31) {
        __syncthreads();   // retires prefetch; protects both buffers
        buf ^= 1;
      }
    }

    // fused epilogue: tanh, row-norm, v accumulation (no ktanh store)
    __syncthreads();                     // all sA reads retired before aliasing
    if (tid < 64) ssrow[tid] = 0.f;
    __syncthreads();

    float b4[4];
#pragma unroll
    for (int ni = 0; ni < 4; ++ni) b4[ni] = wk_b[wave * 64 + ni * 16 + lrow];

#pragma unroll
    for (int mi = 0; mi < 4; ++mi)
#pragma unroll
      for (int ni = 0; ni < 4; ++ni)
#pragma unroll
        for (int r = 0; r < 4; ++r)
          acc[mi][ni][r] = tanhf(acc[mi][ni][r] + b4[ni]);

#pragma unroll
    for (int mi = 0; mi < 4; ++mi)
#pragma unroll
      for (int r = 0; r < 4; ++r) {
        float ps = 0.f;
#pragma unroll
        for (int ni = 0; ni < 4; ++ni) ps += acc[mi][ni][r] * acc[mi][ni][r];
#pragma unroll
        for (int off = 1; off < 16; off <<= 1) ps += __shfl_xor(ps, off);
        if ((lane & 15) == 0)
          atomicAdd(&ssrow[mi * 16 + (lane >> 4) * 4 + r], ps);
      }
    __syncthreads();

    if (tid < 64) {
      int grow = m0 + tid;
      float s = 0.f;
      if (grow < NK) s = wa[grow] / fmaxf(sqrtf(ssrow[tid]), 1e-12f);
      ssrow[tid] = s;                    // replace ss with scale (0 for tail)
    }
    __syncthreads();

    float sc[4][4];
#pragma unroll
    for (int mi = 0; mi < 4; ++mi)
#pragma unroll
      for (int r = 0; r < 4; ++r)
        sc[mi][r] = ssrow[mi * 16 + (lane >> 4) * 4 + r];

#pragma unroll
    for (int ni = 0; ni < 4; ++ni) {
      float cs = 0.f;
#pragma unroll
      for (int mi = 0; mi < 4; ++mi)
#pragma unroll
        for (int r = 0; r < 4; ++r)
          cs += acc[mi][ni][r] * sc[mi][r];
      cs += __shfl_xor(cs, 16);
      cs += __shfl_xor(cs, 32);
      if (lane < 16) atomicAdd(&v[wave * 64 + ni * 16 + lane], cs);
    }
  } else {
    // ---------------- q path: 64x256 tile, fp32 A from global --------------
    const int srow = lane >> 3;                   // 0..7
    const int scol = ((lane & 7) ^ srow) << 3;
    __bf16* sA = (__bf16*)smem;                   // 2 x 4096 elems (16 KB)
    __bf16* sB = (__bf16*)(smem + 16384);         // 2 x 16384 elems (64 KB)
    const int qi = bid - 124;                     // 0..511
    const int m0 = (qi >> 1) * 64;
    const int n0 = (qi & 1) * 256;
    const int wr = wave >> 2;
    const int wc = wave & 3;

    const int arow = tid >> 3;                    // 0..63
    const int acb  = tid & 7;                     // 0..7
    const int aoff = arow * 64 + ((acb ^ (arow & 7)) << 3);
    const float* ap = query + (size_t)(m0 + arow) * K + acb * 8;

    const __bf16* Bp0 = wqbf + (size_t)(n0 + (wave * 4 + 0) * 8 + srow) * K + scol;
    const __bf16* Bp1 = wqbf + (size_t)(n0 + (wave * 4 + 1) * 8 + srow) * K + scol;
    const __bf16* Bp2 = wqbf + (size_t)(n0 + (wave * 4 + 2) * 8 + srow) * K + scol;
    const __bf16* Bp3 = wqbf + (size_t)(n0 + (wave * 4 + 3) * 8 + srow) * K + scol;

    f32x4 acc[2][4] = {};

    {  // prologue: stage tile 0
      float4 x0 = *(const float4*)(ap);
      float4 x1 = *(const float4*)(ap + 4);
      GLOAD_LDS16(Bp0, &sB[(wave * 4 + 0) * 512]);
      GLOAD_LDS16(Bp1, &sB[(wave * 4 + 1) * 512]);
      GLOAD_LDS16(Bp2, &sB[(wave * 4 + 2) * 512]);
      GLOAD_LDS16(Bp3, &sB[(wave * 4 + 3) * 512]);
      *(bf16x8*)&sA[aoff] = cvt8(x0, x1);
      __syncthreads();
    }

    int buf = 0;
    for (int t = 0; t < 16; ++t) {
      const int kk = t * 64;
      float4 x0, x1;
      if (t < 15) {
        x0 = *(const float4*)(ap + kk + 64);     // A loads first (oldest VMEM)
        x1 = *(const float4*)(ap + kk + 68);
        const int ob = buf ^ 1;
        GLOAD_LDS16(Bp0 + kk + 64, &sB[ob * 16384 + (wave * 4 + 0) * 512]);
        GLOAD_LDS16(Bp1 + kk + 64, &sB[ob * 16384 + (wave * 4 + 1) * 512]);
        GLOAD_LDS16(Bp2 + kk + 64, &sB[ob * 16384 + (wave * 4 + 2) * 512]);
        GLOAD_LDS16(Bp3 + kk + 64, &sB[ob * 16384 + (wave * 4 + 3) * 512]);
      }
      const __bf16* sAc = sA + buf * 4096;
      const __bf16* sBc = sB + buf * 16384;
#pragma unroll
      for (int ks = 0; ks < 64; ks += 32) {
        const int cc = (ks >> 3) + chi;
        const int sw = ((cc ^ (lrow & 7)) << 3);
        bf16x8 af[2], bfr[4];
        af[0] = *(const bf16x8*)(&sAc[(wr * 32 + lrow) * 64 + sw]);
        af[1] = *(const bf16x8*)(&sAc[(wr * 32 + 16 + lrow) * 64 + sw]);
#pragma unroll
        for (int ni = 0; ni < 4; ++ni)
          bfr[ni] = *(const bf16x8*)(&sBc[(wc * 64 + ni * 16 + lrow) * 64 + sw]);
#pragma unroll
        for (int ni = 0; ni < 4; ++ni) {
          acc[0][ni] = __builtin_amdgcn_mfma_f32_16x16x32_bf16(af[0], bfr[ni], acc[0][ni], 0, 0, 0);
          acc[1][ni] = __builtin_amdgcn_mfma_f32_16x16x32_bf16(af[1], bfr[ni], acc[1][ni], 0, 0, 0);
        }
      }
      if (t < 15) {
        *(bf16x8*)&sA[(buf ^ 1) * 4096 + aoff] = cvt8(x0, x1);  // waits A regs
        __syncthreads();                  // retires B prefetch + sA write
        buf ^= 1;
      }
    }

    // epilogue: qtanh only (A1 handled by a1_select)
    const int rbase = m0 + wr * 32 + ((lane >> 4) << 2);
    const int cbase = n0 + wc * 64 + (lane & 15);
    float b4[4];
#pragma unroll
    for (int ni = 0; ni < 4; ++ni) b4[ni] = wq_b[cbase + ni * 16];
#pragma unroll
    for (int mi = 0; mi < 2; ++mi)
#pragma unroll
      for (int r = 0; r < 4; ++r) {
        int grow = rbase + mi * 16 + r;
#pragma unroll
        for (int ni = 0; ni < 4; ++ni)
          qtanh[(size_t)grow * HD + cbase + ni * 16] =
              tanhf(acc[mi][ni][r] + b4[ni]);
      }
  }
}

// ---------------------------------------------------------------------------
// Kernel 3: A1[r] = (qtanh[r].v)/max(||qtanh[r]||,1e-12) + wa_b, then the
// LAST block (ticket) runs the exact rank-11469 select over A1 -> scf[0].
// 128 blocks x 1024 threads (16 waves, 8 rows/wave).
// ---------------------------------------------------------------------------
__global__ __launch_bounds__(1024)
void a1_select(const float* __restrict__ qt, const float* __restrict__ v,
               const float* __restrict__ wa_b, float* __restrict__ A1,
               float* __restrict__ scf, unsigned* __restrict__ cnt) {
  __shared__ unsigned wred1[16], wred2[16], wred3[16];
  __shared__ unsigned s_res;
  __shared__ unsigned s_t;
  const int tid = threadIdx.x, lane = tid & 63, wave = tid >> 6;
  const float wab = wa_b[0];
  const float4* vp = (const float4*)(v + lane * 8);
  float4 vv0 = vp[0], vv1 = vp[1];
  const int gw = blockIdx.x * 16 + wave;        // 0..2047
  for (int r = gw; r < NQ; r += 2048) {
    const float4* p = (const float4*)(qt + (size_t)r * HD + lane * 8);
    float4 u = p[0], w = p[1];
    float dot = u.x * vv0.x + u.y * vv0.y + u.z * vv0.z + u.w * vv0.w
              + w.x * vv1.x + w.y * vv1.y + w.z * vv1.z + w.w * vv1.w;
    float ss  = u.x * u.x + u.y * u.y + u.z * u.z + u.w * u.w
              + w.x * w.x + w.y * w.y + w.z * w.z + w.w * w.w;
#pragma unroll
    for (int off = 32; off; off >>= 1) {
      dot += __shfl_xor(dot, off);
      ss  += __shfl_xor(ss, off);
    }
    if (lane == 0) A1[r] = dot / fmaxf(sqrtf(ss), 1e-12f) + wab;
  }

  // last-block ticket: release fence, count, only last block proceeds
  __threadfence();
  __syncthreads();
  if (tid == 0) s_t = atomicAdd(cnt, 1u);
  __syncthreads();
  if (s_t != 127) return;
  __threadfence();                               // acquire side

  volatile const float* A1v = A1;
  unsigned kloc[16];
#pragma unroll 4
  for (int j = 0; j < 16; ++j) kloc[j] = mapf(A1v[j * 1024 + tid]);
  if (tid == 0) s_res = 0u;
  __syncthreads();

  for (int b = 30; b >= 0; b -= 2) {
    const unsigned res = s_res;
    const unsigned t1 = res | (1u << b);
    const unsigned t2 = res | (2u << b);
    const unsigned t3 = res | (3u << b);
    unsigned c1 = 0, c2 = 0, c3 = 0;
#pragma unroll
    for (int j = 0; j < 16; ++j) {
      unsigned k = kloc[j];
      c1 += (k < t1); c2 += (k < t2); c3 += (k < t3);
    }
#pragma unroll
    for (int off = 32; off; off >>= 1) {
      c1 += __shfl_xor(c1, off);
      c2 += __shfl_xor(c2, off);
      c3 += __shfl_xor(c3, off);
    }
    if (lane == 0) { wred1[wave] = c1; wred2[wave] = c2; wred3[wave] = c3; }
    __syncthreads();
    if (tid == 0) {
      unsigned C1 = 0, C2 = 0, C3 = 0;
      for (int w = 0; w < 16; ++w) { C1 += wred1[w]; C2 += wred2[w]; C3 += wred3[w]; }
      unsigned nr = res;
      if (C3 <= RANK_TARGET)      nr = t3;
      else if (C2 <= RANK_TARGET) nr = t2;
      else if (C1 <= RANK_TARGET) nr = t1;
      s_res = nr;
    }
    __syncthreads();
  }
  if (tid == 0) {
    unsigned key = s_res;
    unsigned bits = (key & 0x80000000u) ? (key ^ 0x80000000u) : ~key;
    scf[0] = __uint_as_float(bits);
  }
}

// ---------------------------------------------------------------------------
// Kernel 4: e(r) = exp(thr(A1[r]) - thre) -> out_attn; z' += e*qt row;
// S += e. LAST block then normalizes attn and computes y (volatile re-reads).
// 256 blocks x 256 threads.
// ---------------------------------------------------------------------------
__global__ __launch_bounds__(256)
void expz_fin(const float* __restrict__ A1, const float* __restrict__ qt,
              float* __restrict__ scf, float* __restrict__ e_out,
              float* __restrict__ z, const float* __restrict__ cls_w,
              const float* __restrict__ cls_b, float* __restrict__ y,
              unsigned* __restrict__ cnt) {
  __shared__ float vpart[4][512];
  __shared__ float esum[4];
  __shared__ unsigned s_t;
  const int tid = threadIdx.x, lane = tid & 63, wave = tid >> 6;
  const float thre = scf[0];
  const int gw = blockIdx.x * 4 + wave;
  const int tw = 256 * 4;
  float acc[8] = {0, 0, 0, 0, 0, 0, 0, 0};
  float es = 0.f;
  for (int r = gw; r < NQ; r += tw) {
    float x = A1[r]; x = (x > thre) ? x : 0.f;
    float e = expf(x - thre);
    if (lane == 0) e_out[r] = e;
    es += e;
    const float4* p = (const float4*)(qt + (size_t)r * HD + lane * 8);
    float4 u = p[0], w = p[1];
    acc[0] += e * u.x; acc[1] += e * u.y; acc[2] += e * u.z; acc[3] += e * u.w;
    acc[4] += e * w.x; acc[5] += e * w.y; acc[6] += e * w.z; acc[7] += e * w.w;
  }
  if (lane == 0) esum[wave] = es;   // es identical across lanes of the wave
#pragma unroll
  for (int j = 0; j < 8; ++j) vpart[wave][lane * 8 + j] = acc[j];
  __syncthreads();
  for (int c = tid; c < 512; c += 256)
    atomicAdd(&z[c], vpart[0][c] + vpart[1][c] + vpart[2][c] + vpart[3][c]);
  if (tid == 0) atomicAdd(&scf[2], esum[0] + esum[1] + esum[2] + esum[3]);

  // last-block ticket
  __threadfence();
  __syncthreads();
  if (tid == 0) s_t = atomicAdd(cnt, 1u);
  __syncthreads();
  if (s_t != 255) return;
  __threadfence();                               // acquire side

  const float S = *(volatile float*)&scf[2];
  const float invZ = 1.f / S;
  volatile const float* ev = e_out;
  for (int i = tid; i < NQ; i += 256) e_out[i] = ev[i] * invZ;
  if (tid < 64) {
    volatile const float* zv = z;
    float dot = 0.f;
#pragma unroll
    for (int j = 0; j < 8; ++j)
      dot += zv[tid * 8 + j] * cls_w[tid * 8 + j];
#pragma unroll
    for (int off = 32; off; off >>= 1) dot += __shfl_xor(dot, off);
    if (tid == 0) y[0] = dot * invZ + cls_b[0];
  }
}

// ---------------------------------------------------------------------------
// Workspace layout (bytes). Max end = 52,498,688.
// v/z/scf contiguous (zeroed as 1088 uints by conv_wk block 0); tickets live
// at scf[8] and scf[9] (inside the zeroed region -> replay-safe).
// ---------------------------------------------------------------------------
#define OFF_WQBF 0u
#define OFF_WKBF 1048576u
#define OFF_KBF  2097152u      // 16.25 MB, ends 18,343,936
#define OFF_QT   18874368u     // 33.55 MB, ends 52,428,800
#define OFF_A1   52428800u     // 64 KB
#define OFF_V    52494336u     // 2 KB
#define OFF_Z    52496384u     // 2 KB
#define OFF_SC   52498432u     // 256 B, ends 52,498,688

extern "C" void kernel_launch(void* const* d_in, const int* in_sizes, int n_in,
                              void* d_out, int out_size, void* d_ws, size_t ws_size,
                              hipStream_t stream) {
  const float* query = (const float*)d_in[0];
  const float* key_x = (const float*)d_in[1];
  const float* wq_w  = (const float*)d_in[2];
  const float* wq_b  = (const float*)d_in[3];
  const float* wk_w  = (const float*)d_in[4];
  const float* wk_b  = (const float*)d_in[5];
  const float* wa_w  = (const float*)d_in[6];
  const float* wa_b  = (const float*)d_in[7];
  const float* cls_w = (const float*)d_in[8];
  const float* cls_b = (const float*)d_in[9];
  float* out = (float*)d_out;

  char* ws = (char*)d_ws;
  __bf16* wqbf  = (__bf16*)(ws + OFF_WQBF);
  __bf16* wkbf  = (__bf16*)(ws + OFF_WKBF);
  __bf16* kbf   = (__bf16*)(ws + OFF_KBF);
  float*  qtanh = (float*)(ws + OFF_QT);
  float*  A1    = (float*)(ws + OFF_A1);
  float*  v     = (float*)(ws + OFF_V);
  float*  z     = (float*)(ws + OFF_Z);
  float*  scf   = (float*)(ws + OFF_SC);
  unsigned* cnt1 = (unsigned*)(scf + 8);
  unsigned* cnt2 = (unsigned*)(scf + 9);
  float*  out_attn = out + 1;

  // 1: convert key + weights to bf16; zero v/z/scf (incl. tickets)
  conv_wk<<<2048, 256, 0, stream>>>(wq_w, wk_w, key_x, wqbf, wkbf, kbf,
                                    (unsigned*)v);

  // 2: mega launch — k-GEMM (BK=32 dbuf, fused v) co-scheduled with q-GEMM
  mega_gemms<<<636, 512, 0, stream>>>(kbf, wkbf, wk_b, wa_w, v,
                                      query, wqbf, wq_b, qtanh);

  // 3: A1 pass + last-block rank-11469 select
  a1_select<<<128, 1024, 0, stream>>>(qtanh, v, wa_b, A1, scf, cnt1);

  // 4: expz + last-block normalize/finalize
  expz_fin<<<256, 256, 0, stream>>>(A1, qtanh, scf, out_attn, z,
                                    cls_w, cls_b, out, cnt2);
}